// Round 4
// baseline (965.676 us; speedup 1.0000x reference)
//
#include <hip/hip_runtime.h>
#include <stdint.h>

#define NN 50000
#define NE 600000
#define DD 128
#define MD 64

__device__ __forceinline__ float b2f(unsigned int u) {
    union { unsigned int i; float f; } v; v.i = u << 16; return v.f;
}
__device__ __forceinline__ unsigned short f2b(float f) {
    union { float f; unsigned int i; } v; v.f = f;
    unsigned int r = v.i + 0x7fffu + ((v.i >> 16) & 1u);
    return (unsigned short)(r >> 16);
}

// ---------------- zero fill ----------------
__global__ void k_zero(int* __restrict__ p, int n) {
    int i = blockIdx.x * 256 + threadIdx.x;
    if (i < n) p[i] = 0;
}

// ---------------- degree histograms ----------------
__global__ void k_degrees(const int* __restrict__ s0, const int* __restrict__ d0,
                          const int* __restrict__ s1, const int* __restrict__ d1,
                          int* __restrict__ deg) {
    int e = blockIdx.x * 256 + threadIdx.x;
    if (e >= NE) return;
    atomicAdd(&deg[s0[e]], 1);
    atomicAdd(&deg[NN + d0[e]], 1);
    atomicAdd(&deg[2 * NN + s1[e]], 1);
    atomicAdd(&deg[3 * NN + d1[e]], 1);
}

__global__ void k_rs(const int* __restrict__ deg, float* __restrict__ rs) {
    int i = blockIdx.x * 256 + threadIdx.x;
    if (i < 4 * NN) rs[i] = rsqrtf(fmaxf((float)deg[i], 1.0f));
}

// ---------------- ELL adjacency ----------------
__global__ void k_build_ell(const int* __restrict__ s0, const int* __restrict__ d0,
                            const int* __restrict__ s1, const int* __restrict__ d1,
                            int* __restrict__ cur, int* __restrict__ ell0, int* __restrict__ ell1) {
    int e = blockIdx.x * 256 + threadIdx.x;
    if (e >= NE) return;
    int dd = d0[e];
    int p = atomicAdd(&cur[dd], 1);
    if (p < MD) ell0[dd * MD + p] = s0[e];
    dd = d1[e];
    p = atomicAdd(&cur[NN + dd], 1);
    if (p < MD) ell1[dd * MD + p] = s1[e];
}

// ---------------- scale+cast: fp32 x * rsqrt(dout) -> bf16 table ----------------
__global__ void k_scale_cast(const float* __restrict__ xA, const float* __restrict__ xB,
                             const float* __restrict__ rs,
                             unsigned short* __restrict__ oA, unsigned short* __restrict__ oB) {
    int idx2 = blockIdx.x * 256 + threadIdx.x;      // float2 units
    if (idx2 >= NN * 64) return;
    const float* x = blockIdx.y ? xB : xA;
    const float* r = blockIdx.y ? (rs + 2 * NN) : rs;
    unsigned short* o = blockIdx.y ? oB : oA;
    float2 v = ((const float2*)x)[idx2];
    float sc = r[idx2 >> 6];
    ((unsigned int*)o)[idx2] = (unsigned int)f2b(v.x * sc) | ((unsigned int)f2b(v.y * sc) << 16);
}

// ---------------- aggregation over bf16 table, fp32 accumulate ----------------
__global__ void k_agg(const unsigned short* __restrict__ table, const int* __restrict__ ell,
                      const int* __restrict__ deg, const float* __restrict__ rs,
                      unsigned short* __restrict__ out) {
    int wid = (blockIdx.x * 256 + threadIdx.x) >> 6;
    int lane = threadIdx.x & 63;
    if (wid >= NN) return;
    int d = deg[wid];
    d = (d < 0) ? 0 : ((d > MD) ? MD : d);
    const int* el = ell + (size_t)wid * MD;
    float a0 = 0.f, a1 = 0.f;
    int i = 0;
    for (; i + 4 <= d; i += 4) {
        int e0 = el[i], e1 = el[i + 1], e2 = el[i + 2], e3 = el[i + 3];
        unsigned int u0 = *(const unsigned int*)(table + (size_t)e0 * DD + lane * 2);
        unsigned int u1 = *(const unsigned int*)(table + (size_t)e1 * DD + lane * 2);
        unsigned int u2 = *(const unsigned int*)(table + (size_t)e2 * DD + lane * 2);
        unsigned int u3 = *(const unsigned int*)(table + (size_t)e3 * DD + lane * 2);
        a0 += b2f(u0 & 0xffffu) + b2f(u1 & 0xffffu) + b2f(u2 & 0xffffu) + b2f(u3 & 0xffffu);
        a1 += b2f(u0 >> 16) + b2f(u1 >> 16) + b2f(u2 >> 16) + b2f(u3 >> 16);
    }
    for (; i < d; ++i) {
        int e0 = el[i];
        unsigned int u0 = *(const unsigned int*)(table + (size_t)e0 * DD + lane * 2);
        a0 += b2f(u0 & 0xffffu);
        a1 += b2f(u0 >> 16);
    }
    float sc = rs[wid];
    *(unsigned int*)(out + (size_t)wid * DD + lane * 2) =
        (unsigned int)f2b(a0 * sc) | ((unsigned int)f2b(a1 * sc) << 16);
}

// ---------------- VALU GEMM: 128-K slice, A bf16, W fp32(global)->bf16(LDS) ----------------
// out[row][col] = post( sum_k A[row][aoff+k] * W[k][col] ), col in [0,128)
// OF32: write fp32 accumulator buffer. AIN: add fp32 accumulator buffer, write bf16.
template<int RELU, int BIAS, int PS, int OF32, int AIN>
__global__ void k_gemm(const unsigned short* __restrict__ A, int lda, int aoff,
                       const float* __restrict__ W,
                       const float* __restrict__ bias,
                       const float* __restrict__ ps,
                       const float* __restrict__ ain,
                       float* __restrict__ fout,
                       unsigned short* __restrict__ bout, int ldo, int ocol) {
    __shared__ __align__(16) unsigned short Wl[128 * 128];   // bf16, 32KB
    int tid = threadIdx.x, lane = tid & 63, w = tid >> 6;
    // stage W once: 16384 fp32 -> bf16
#pragma unroll
    for (int i = 0; i < 16; ++i) {
        int c = tid + i * 256;                               // float4 chunk
        float4 v = *(const float4*)(W + c * 4);
        uint2 p;
        p.x = (unsigned int)f2b(v.x) | ((unsigned int)f2b(v.y) << 16);
        p.y = (unsigned int)f2b(v.z) | ((unsigned int)f2b(v.w) << 16);
        *(uint2*)(Wl + c * 4) = p;
    }
    __syncthreads();
    for (int row4 = blockIdx.x * 4; row4 < NN; row4 += gridDim.x * 4) {
        int row = row4 + w;
        float acc0 = 0.f, acc1 = 0.f;
        unsigned int ap = *(const unsigned int*)(A + (size_t)row * lda + aoff + 2 * lane);
#pragma unroll 16
        for (int j = 0; j < 64; ++j) {
            unsigned int av = __shfl((int)ap, j, 64);
            float x0 = b2f(av & 0xffffu), x1 = b2f(av >> 16);
            unsigned int w0 = *(const unsigned int*)(Wl + (2 * j) * 128 + 2 * lane);
            unsigned int w1 = *(const unsigned int*)(Wl + (2 * j + 1) * 128 + 2 * lane);
            acc0 += x0 * b2f(w0 & 0xffffu) + x1 * b2f(w1 & 0xffffu);
            acc1 += x0 * b2f(w0 >> 16) + x1 * b2f(w1 >> 16);
        }
        if (OF32) {
            *(float2*)(fout + (size_t)row * 128 + 2 * lane) = make_float2(acc0, acc1);
        } else {
            float v0 = acc0, v1 = acc1;
            if (AIN) {
                float2 a = *(const float2*)(ain + (size_t)row * 128 + 2 * lane);
                v0 += a.x; v1 += a.y;
            }
            if (BIAS) { v0 += bias[2 * lane]; v1 += bias[2 * lane + 1]; }
            if (RELU) { v0 = fmaxf(v0, 0.f); v1 = fmaxf(v1, 0.f); }
            if (PS) { float s = ps[row]; v0 *= s; v1 *= s; }
            *(unsigned int*)(bout + (size_t)row * ldo + ocol + 2 * lane) =
                (unsigned int)f2b(v0) | ((unsigned int)f2b(v1) << 16);
        }
    }
}

// ---------------- BN statistics (h1 bf16) ----------------
__global__ void k_bnstats(const unsigned short* __restrict__ h1, float* __restrict__ sums) {
    int col = threadIdx.x & 127;
    int half = threadIdx.x >> 7;
    int r0 = blockIdx.x * 500;
    float s = 0.f, s2 = 0.f;
    for (int r = r0 + half; r < r0 + 500; r += 2) {
        float v = b2f((unsigned int)h1[(size_t)r * DD + col]);
        s += v; s2 += v * v;
    }
    __shared__ float ls[256], ls2[256];
    ls[threadIdx.x] = s; ls2[threadIdx.x] = s2;
    __syncthreads();
    if (half == 0) {
        atomicAdd(&sums[col], ls[col] + ls[col + 128]);
        atomicAdd(&sums[col + 128], ls2[col] + ls2[col + 128]);
    }
}

__global__ void k_bnfinal(const float* __restrict__ sums,
                          const float* __restrict__ gamma, const float* __restrict__ beta,
                          float* __restrict__ bn) {
    int c = threadIdx.x;
    if (c >= 128) return;
    const float inv = 1.0f / (float)NN;
    float mu = sums[c] * inv;
    float var = sums[c + 128] * inv - mu * mu;
    float a = gamma[c] * rsqrtf(var + 1e-5f);
    bn[c] = a;
    bn[c + 128] = beta[c] - mu * a;
}

// ---------------- head: out fp32 ----------------
__global__ void k_head(const unsigned short* __restrict__ h1, const float* __restrict__ bn,
                       const float* __restrict__ Wm2, float* __restrict__ out) {
    int row = blockIdx.x * 4 + (threadIdx.x >> 6);
    int lane = threadIdx.x & 63;
    if (row >= NN) return;
    float h0 = b2f((unsigned int)h1[(size_t)row * DD + lane]);
    float h64 = b2f((unsigned int)h1[(size_t)row * DD + lane + 64]);
    float v0 = fmaxf(h0 * bn[lane] + bn[128 + lane], 0.f);
    float v1 = fmaxf(h64 * bn[lane + 64] + bn[128 + lane + 64], 0.f);
    float2 wa = *(const float2*)(Wm2 + lane * 2);
    float2 wb = *(const float2*)(Wm2 + (lane + 64) * 2);
    float acc0 = v0 * wa.x + v1 * wb.x;
    float acc1 = v0 * wa.y + v1 * wb.y;
#pragma unroll
    for (int off = 32; off > 0; off >>= 1) {
        acc0 += __shfl_down(acc0, off, 64);
        acc1 += __shfl_down(acc1, off, 64);
    }
    if (lane == 0) *(float2*)(out + (size_t)row * 2) = make_float2(acc0, acc1);
}

// ---------------- canary: fp32 sentinel (finally visible!) ----------------
__global__ void k_check(const int* __restrict__ deg, const unsigned short* __restrict__ s1,
                        const unsigned short* __restrict__ h2, const unsigned short* __restrict__ h1,
                        float* __restrict__ out, int hostFail) {
    if (threadIdx.x != 0 || blockIdx.x != 0) return;
    float sentinel = 0.f;
    if (hostFail) {
        sentinel = (float)hostFail;
    } else {
        int d = deg[NN + 1234];
        if (d < 0 || d > 100000) sentinel = 100.0f;            // deg poison -> never computed
        else {
            float sa = 0.f;
            for (int j = 0; j < DD; ++j) sa += fabsf(b2f((unsigned int)s1[777 * DD + j]));
            if (!(sa > 0.f)) sentinel = 200.0f;                // conv1 chain dead/NaN
            else {
                float sb = 0.f;
                for (int j = 0; j < 256; ++j) sb += fabsf(b2f((unsigned int)h2[(size_t)555 * 256 + j]));
                if (!(sb > 0.f)) sentinel = 300.0f;            // conv2 chain dead/NaN
                else {
                    float sc = 0.f;
                    for (int j = 0; j < DD; ++j) sc += fabsf(b2f((unsigned int)h1[(size_t)444 * DD + j]));
                    if (!(sc > 0.f)) sentinel = 400.0f;        // MLP dead/NaN
                }
            }
        }
    }
    if (sentinel != 0.f) out[0] = sentinel;
}

// ---------------- workspace layout (bytes) ----------------
static constexpr size_t O_DEG  = 0;                   // 4N int
static constexpr size_t O_CUR  = 800000;              // 2N int
static constexpr size_t O_RS   = 1200128;             // 4N f32
static constexpr size_t O_ELL0 = 2000128;             // N*64 int (12.8M); h2 overlays ell0+ell1
static constexpr size_t O_ELL1 = 14800128;
static constexpr size_t O_H2   = 2000128;             // N*256 bf16 = 25.6M (after ells die)
static constexpr size_t O_S0   = 27600128;            // N*128 bf16 (12.8M); h1 overlays after s0 dies
static constexpr size_t O_H1   = 27600128;
static constexpr size_t O_S1   = 40400128;            // 12.8M (survives to end - canary)
static constexpr size_t O_AG0  = 53200128;            // 12.8M; h1acc(f32 25.6M) overlays ag0+ag1
static constexpr size_t O_AG1  = 66000128;
static constexpr size_t O_HACC = 53200128;
static constexpr size_t O_BNS  = 78800128;            // 256 f32
static constexpr size_t O_BNAB = 78801152;            // 256 f32
static constexpr size_t O_END  = 78802176;            // ~75.2 MB

extern "C" void kernel_launch(void* const* d_in, const int* in_sizes, int n_in,
                              void* d_out, int out_size, void* d_ws, size_t ws_size,
                              hipStream_t stream) {
    const float* xA    = (const float*)d_in[0];
    const float* xB    = (const float*)d_in[1];
    const int* src0 = (const int*)d_in[2];
    const int* dst0 = (const int*)d_in[3];
    const int* src1 = (const int*)d_in[4];
    const int* dst1 = (const int*)d_in[5];
    const float* W1r0  = (const float*)d_in[6];
    const float* b1r0  = (const float*)d_in[7];
    const float* W1r1  = (const float*)d_in[8];
    const float* b1r1  = (const float*)d_in[9];
    const float* W2r0  = (const float*)d_in[10];
    const float* b2r0  = (const float*)d_in[11];
    const float* W2r1  = (const float*)d_in[12];
    const float* b2r1  = (const float*)d_in[13];
    const float* Wm1   = (const float*)d_in[14];
    const float* gamma = (const float*)d_in[15];
    const float* beta  = (const float*)d_in[16];
    const float* Wm2   = (const float*)d_in[17];

    char* ws = (char*)d_ws;
    int*   deg  = (int*)(ws + O_DEG);
    int*   cur  = (int*)(ws + O_CUR);
    float* rs   = (float*)(ws + O_RS);
    int*   ell0 = (int*)(ws + O_ELL0);
    int*   ell1 = (int*)(ws + O_ELL1);
    unsigned short* s0   = (unsigned short*)(ws + O_S0);
    unsigned short* s1   = (unsigned short*)(ws + O_S1);
    unsigned short* ag0  = (unsigned short*)(ws + O_AG0);
    unsigned short* ag1  = (unsigned short*)(ws + O_AG1);
    unsigned short* h2   = (unsigned short*)(ws + O_H2);
    unsigned short* h1   = (unsigned short*)(ws + O_H1);
    float* hacc = (float*)(ws + O_HACC);
    float* bns  = (float*)(ws + O_BNS);
    float* bnab = (float*)(ws + O_BNAB);
    float* out  = (float*)d_out;

    int hostFail = 0;
    if (ws_size < O_END) hostFail = 700;
    else if (n_in < 18) hostFail = 900;
    else if (in_sizes[0] != NN * DD) hostFail = 800;
    else if (in_sizes[2] != NE) hostFail = 850;

    if (!hostFail) {
        k_zero<<<(300000 + 255) / 256, 256, 0, stream>>>(deg, 300000);   // deg + cur
        k_zero<<<1, 256, 0, stream>>>((int*)bns, 256);

        const int EB = (NE + 255) / 256;
        k_degrees<<<EB, 256, 0, stream>>>(src0, dst0, src1, dst1, deg);
        k_rs<<<(4 * NN + 255) / 256, 256, 0, stream>>>(deg, rs);
        k_build_ell<<<EB, 256, 0, stream>>>(src0, dst0, src1, dst1, cur, ell0, ell1);
        k_scale_cast<<<dim3(12500, 2), 256, 0, stream>>>(xA, xB, rs, s0, s1);

        const int AB = (NN * 64 + 255) / 256;   // wave per node
        const int GB = 1024;

        // conv1 r0 (A->B): agg(xA-table over ell0) -> relu(.@W1r0+b)*rs_dout_r1 -> s0 (hB table)
        k_agg<<<AB, 256, 0, stream>>>(s0, ell0, deg + NN, rs + NN, ag0);
        k_gemm<1,1,1,0,0><<<GB, 256, 0, stream>>>(ag0, 128, 0, W1r0, b1r0, rs + 2 * NN, nullptr, nullptr, s0, 128, 0);
        // conv1 r1 (B->A): -> s1 (hA table, pre-scaled by rs_dout_r0)
        k_agg<<<AB, 256, 0, stream>>>(s1, ell1, deg + 3 * NN, rs + 3 * NN, ag0);
        k_gemm<1,1,1,0,0><<<GB, 256, 0, stream>>>(ag0, 128, 0, W1r1, b1r1, rs, nullptr, nullptr, s1, 128, 0);
        // conv2 aggregations (both before gemms: ells die, h2 overlays them)
        k_agg<<<AB, 256, 0, stream>>>(s1, ell0, deg + NN, rs + NN, ag0);        // src hA, r0 -> dst B
        k_agg<<<AB, 256, 0, stream>>>(s0, ell1, deg + 3 * NN, rs + 3 * NN, ag1); // src hB, r1 -> dst A
        // conv2 gemms -> h2 = [h2A | h2B]
        k_gemm<0,1,0,0,0><<<GB, 256, 0, stream>>>(ag0, 128, 0, W2r0, b2r0, nullptr, nullptr, nullptr, h2, 256, 128);
        k_gemm<0,1,0,0,0><<<GB, 256, 0, stream>>>(ag1, 128, 0, W2r1, b2r1, nullptr, nullptr, nullptr, h2, 256, 0);
        // MLP: h1 = h2 @ Wm1 (K=256 via two 128-K accumulating launches)
        k_gemm<0,0,0,1,0><<<GB, 256, 0, stream>>>(h2, 256, 0,   Wm1,         nullptr, nullptr, nullptr, hacc, nullptr, 128, 0);
        k_gemm<0,0,0,0,1><<<GB, 256, 0, stream>>>(h2, 256, 128, Wm1 + 16384, nullptr, nullptr, hacc, nullptr, h1, 128, 0);

        k_bnstats<<<100, 256, 0, stream>>>(h1, bns);
        k_bnfinal<<<1, 128, 0, stream>>>(bns, gamma, beta, bnab);
        k_head<<<12500, 256, 0, stream>>>(h1, bnab, Wm2, out);
    }
    k_check<<<1, 64, 0, stream>>>(deg, s1, h2, h1, out, hostFail);
}

// Round 5
// 554.862 us; speedup vs baseline: 1.7404x; 1.7404x over previous
//
#include <hip/hip_runtime.h>
#include <stdint.h>

#define NN 50000
#define NE 600000
#define DD 128
#define MD 64

typedef __attribute__((ext_vector_type(8))) short s16x8;
typedef __attribute__((ext_vector_type(4))) float f32x4;

__device__ __forceinline__ float b2f(unsigned int u) {
    union { unsigned int i; float f; } v; v.i = u << 16; return v.f;
}
__device__ __forceinline__ unsigned short f2b(float f) {
    union { float f; unsigned int i; } v; v.f = f;
    unsigned int r = v.i + 0x7fffu + ((v.i >> 16) & 1u);
    return (unsigned short)(r >> 16);
}

// ---------------- zero fill ----------------
__global__ void k_zero(int* __restrict__ p, int n) {
    int i = blockIdx.x * 256 + threadIdx.x;
    if (i < n) p[i] = 0;
}

// ---------------- merged: src histograms + ELL build (din = ELL position counter) ----------------
// deg[0..N)   = dout r0 (hist s0)      deg[N..2N)  = din r0 (ELL0 fill count)
// deg[2N..3N) = dout r1 (hist s1)      deg[3N..4N) = din r1 (ELL1 fill count)
__global__ void k_build(const int* __restrict__ s0, const int* __restrict__ d0,
                        const int* __restrict__ s1, const int* __restrict__ d1,
                        int* __restrict__ deg, int* __restrict__ ell0, int* __restrict__ ell1) {
    int e = blockIdx.x * 256 + threadIdx.x;
    if (e >= NE) return;
    int a = s0[e], b = d0[e], c = s1[e], d = d1[e];
    atomicAdd(&deg[a], 1);
    atomicAdd(&deg[2 * NN + c], 1);
    int p0 = atomicAdd(&deg[NN + b], 1);
    if (p0 < MD) ell0[b * MD + p0] = a;
    int p1 = atomicAdd(&deg[3 * NN + d], 1);
    if (p1 < MD) ell1[d * MD + p1] = c;
}

__global__ void k_rs(const int* __restrict__ deg, float* __restrict__ rs) {
    int i = blockIdx.x * 256 + threadIdx.x;
    if (i < 4 * NN) rs[i] = rsqrtf(fmaxf((float)deg[i], 1.0f));
}

// ---------------- scale+cast: fp32 x * rsqrt(dout) -> bf16 table ----------------
__global__ void k_scale_cast(const float* __restrict__ xA, const float* __restrict__ xB,
                             const float* __restrict__ rs,
                             unsigned short* __restrict__ oA, unsigned short* __restrict__ oB) {
    int idx2 = blockIdx.x * 256 + threadIdx.x;      // float2 units
    if (idx2 >= NN * 64) return;
    const float* x = blockIdx.y ? xB : xA;
    const float* r = blockIdx.y ? (rs + 2 * NN) : rs;
    unsigned short* o = blockIdx.y ? oB : oA;
    float2 v = ((const float2*)x)[idx2];
    float sc = r[idx2 >> 6];
    ((unsigned int*)o)[idx2] = (unsigned int)f2b(v.x * sc) | ((unsigned int)f2b(v.y * sc) << 16);
}

// ---------------- weight prep: fp32 [K][128] -> bf16 [128][K] (transposed) ----------------
__global__ void k_prepw(const float* __restrict__ W1r0, const float* __restrict__ W1r1,
                        const float* __restrict__ W2r0, const float* __restrict__ W2r1,
                        const float* __restrict__ Wm1, unsigned short* __restrict__ wt) {
    int which = blockIdx.y;
    const float* W; unsigned short* Wt; int K;
    if (which == 0)      { W = W1r0; Wt = wt;         K = 128; }
    else if (which == 1) { W = W1r1; Wt = wt + 16384; K = 128; }
    else if (which == 2) { W = W2r0; Wt = wt + 32768; K = 128; }
    else if (which == 3) { W = W2r1; Wt = wt + 49152; K = 128; }
    else                 { W = Wm1;  Wt = wt + 65536; K = 256; }
    int t = blockIdx.x * 256 + threadIdx.x;
    if (t >= K * 128) return;
    int k = t >> 7, j = t & 127;
    Wt[(size_t)j * K + k] = f2b(W[t]);
}

// ---------------- aggregation: wave/node, edge list in registers, 16B gathers ----------------
__global__ void k_agg(const unsigned short* __restrict__ table, const int* __restrict__ ell,
                      const int* __restrict__ deg, const float* __restrict__ rs,
                      unsigned short* __restrict__ out) {
    int wid = (blockIdx.x * 256 + threadIdx.x) >> 6;
    int lane = threadIdx.x & 63;
    if (wid >= NN) return;
    int d = deg[wid];
    d = (d < 0) ? 0 : ((d > MD) ? MD : d);
    const int* el = ell + (size_t)wid * MD;
    int myE = (lane < d) ? el[lane] : 0;            // whole edge list in one load
    int q = lane >> 4, s = lane & 15;               // quad handles every 4th edge, 16B segment s
    float a0=0.f,a1=0.f,a2=0.f,a3=0.f,a4=0.f,a5=0.f,a6=0.f,a7=0.f;
    for (int i = 0; i < d; i += 8) {
        int i0 = i + q, i1 = i + 4 + q;
        int e0 = __shfl(myE, i0, 64);
        int e1 = __shfl(myE, i1, 64);
        if (i0 < d) {
            uint4 u = *(const uint4*)(table + (size_t)e0 * DD + s * 8);
            a0 += b2f(u.x & 0xffffu); a1 += b2f(u.x >> 16);
            a2 += b2f(u.y & 0xffffu); a3 += b2f(u.y >> 16);
            a4 += b2f(u.z & 0xffffu); a5 += b2f(u.z >> 16);
            a6 += b2f(u.w & 0xffffu); a7 += b2f(u.w >> 16);
        }
        if (i1 < d) {
            uint4 u = *(const uint4*)(table + (size_t)e1 * DD + s * 8);
            a0 += b2f(u.x & 0xffffu); a1 += b2f(u.x >> 16);
            a2 += b2f(u.y & 0xffffu); a3 += b2f(u.y >> 16);
            a4 += b2f(u.z & 0xffffu); a5 += b2f(u.z >> 16);
            a6 += b2f(u.w & 0xffffu); a7 += b2f(u.w >> 16);
        }
    }
    // reduce across the 4 quads (xor 16, 32)
    a0 += __shfl_xor(a0, 16, 64); a0 += __shfl_xor(a0, 32, 64);
    a1 += __shfl_xor(a1, 16, 64); a1 += __shfl_xor(a1, 32, 64);
    a2 += __shfl_xor(a2, 16, 64); a2 += __shfl_xor(a2, 32, 64);
    a3 += __shfl_xor(a3, 16, 64); a3 += __shfl_xor(a3, 32, 64);
    a4 += __shfl_xor(a4, 16, 64); a4 += __shfl_xor(a4, 32, 64);
    a5 += __shfl_xor(a5, 16, 64); a5 += __shfl_xor(a5, 32, 64);
    a6 += __shfl_xor(a6, 16, 64); a6 += __shfl_xor(a6, 32, 64);
    a7 += __shfl_xor(a7, 16, 64); a7 += __shfl_xor(a7, 32, 64);
    if (q == 0) {
        float sc = rs[wid];
        uint4 o;
        o.x = (unsigned int)f2b(a0 * sc) | ((unsigned int)f2b(a1 * sc) << 16);
        o.y = (unsigned int)f2b(a2 * sc) | ((unsigned int)f2b(a3 * sc) << 16);
        o.z = (unsigned int)f2b(a4 * sc) | ((unsigned int)f2b(a5 * sc) << 16);
        o.w = (unsigned int)f2b(a6 * sc) | ((unsigned int)f2b(a7 * sc) << 16);
        *(uint4*)(out + (size_t)wid * DD + s * 8) = o;
    }
}

// ---------------- MFMA GEMM: out = post( A[NN x K](bf16) @ W[K x 128] ) ----------------
// Wt layout [128 cols][K] bf16. 64 rows x 128 cols per block, 4 waves, mfma 16x16x32.
template<int RELU, int BIAS, int PS>
__global__ __launch_bounds__(256)
void k_gemm(const unsigned short* __restrict__ A, int lda, int K,
            const unsigned short* __restrict__ Wt,
            const float* __restrict__ bias, const float* __restrict__ ps,
            unsigned short* __restrict__ out, int ldo, int ocol) {
    __shared__ __align__(16) unsigned short Ad[64 * 128];
    __shared__ __align__(16) unsigned short Wl[128 * 128];
    int tid = threadIdx.x;
    int row0 = blockIdx.x * 64;
    f32x4 acc[8];
#pragma unroll
    for (int c = 0; c < 8; ++c) acc[c] = (f32x4){0.f, 0.f, 0.f, 0.f};
    int lane = tid & 63, w = tid >> 6, m = lane & 15, q = lane >> 4;

    for (int p = 0; p < K; p += 128) {
#pragma unroll
        for (int i = 0; i < 4; ++i) {
            int c = tid + i * 256;                   // 1024 x 16B
            int r = c >> 4, c8 = c & 15;
            uint4 v = make_uint4(0u, 0u, 0u, 0u);
            if (row0 + r < NN) v = *(const uint4*)(A + (size_t)(row0 + r) * lda + p + c8 * 8);
            *(uint4*)(Ad + r * 128 + c8 * 8) = v;
        }
#pragma unroll
        for (int i = 0; i < 8; ++i) {
            int c = tid + i * 256;                   // 2048 x 16B
            int j = c >> 4, c8 = c & 15;
            *(uint4*)(Wl + j * 128 + c8 * 8) = *(const uint4*)(Wt + (size_t)j * K + p + c8 * 8);
        }
        __syncthreads();
#pragma unroll
        for (int kt = 0; kt < 4; ++kt) {
            s16x8 a = *(const s16x8*)(Ad + (w * 16 + m) * 128 + kt * 32 + q * 8);
#pragma unroll
            for (int c = 0; c < 8; ++c) {
                s16x8 b = *(const s16x8*)(Wl + (c * 16 + m) * 128 + kt * 32 + q * 8);
                acc[c] = __builtin_amdgcn_mfma_f32_16x16x32_bf16(a, b, acc[c], 0, 0, 0);
            }
        }
        __syncthreads();
    }
    // epilogue: C layout col = lane&15 (within 16-block), row = (lane>>4)*4 + reg
#pragma unroll
    for (int c = 0; c < 8; ++c) {
        int col = c * 16 + m;
        float bv = BIAS ? bias[col] : 0.f;
#pragma unroll
        for (int r = 0; r < 4; ++r) {
            int row = row0 + w * 16 + q * 4 + r;
            if (row < NN) {
                float v = acc[c][r] + bv;
                if (RELU) v = fmaxf(v, 0.f);
                if (PS) v *= ps[row];
                out[(size_t)row * ldo + ocol + col] = f2b(v);
            }
        }
    }
}

// ---------------- BN statistics ----------------
__global__ void k_bnstats(const unsigned short* __restrict__ h1, float* __restrict__ sums) {
    int col = threadIdx.x & 127;
    int half = threadIdx.x >> 7;
    int r0 = blockIdx.x * 500;
    float s = 0.f, s2 = 0.f;
    for (int r = r0 + half; r < r0 + 500; r += 2) {
        float v = b2f((unsigned int)h1[(size_t)r * DD + col]);
        s += v; s2 += v * v;
    }
    __shared__ float ls[256], ls2[256];
    ls[threadIdx.x] = s; ls2[threadIdx.x] = s2;
    __syncthreads();
    if (half == 0) {
        atomicAdd(&sums[col], ls[col] + ls[col + 128]);
        atomicAdd(&sums[col + 128], ls2[col] + ls2[col + 128]);
    }
}

__global__ void k_bnfinal(const float* __restrict__ sums,
                          const float* __restrict__ gamma, const float* __restrict__ beta,
                          float* __restrict__ bn) {
    int c = threadIdx.x;
    if (c >= 128) return;
    const float inv = 1.0f / (float)NN;
    float mu = sums[c] * inv;
    float var = sums[c + 128] * inv - mu * mu;
    float a = gamma[c] * rsqrtf(var + 1e-5f);
    bn[c] = a;
    bn[c + 128] = beta[c] - mu * a;
}

// ---------------- head: out fp32 ----------------
__global__ void k_head(const unsigned short* __restrict__ h1, const float* __restrict__ bn,
                       const float* __restrict__ Wm2, float* __restrict__ out) {
    int row = blockIdx.x * 4 + (threadIdx.x >> 6);
    int lane = threadIdx.x & 63;
    if (row >= NN) return;
    float h0 = b2f((unsigned int)h1[(size_t)row * DD + lane]);
    float h64 = b2f((unsigned int)h1[(size_t)row * DD + lane + 64]);
    float v0 = fmaxf(h0 * bn[lane] + bn[128 + lane], 0.f);
    float v1 = fmaxf(h64 * bn[lane + 64] + bn[128 + lane + 64], 0.f);
    float2 wa = *(const float2*)(Wm2 + lane * 2);
    float2 wb = *(const float2*)(Wm2 + (lane + 64) * 2);
    float acc0 = v0 * wa.x + v1 * wb.x;
    float acc1 = v0 * wa.y + v1 * wb.y;
#pragma unroll
    for (int off = 32; off > 0; off >>= 1) {
        acc0 += __shfl_down(acc0, off, 64);
        acc1 += __shfl_down(acc1, off, 64);
    }
    if (lane == 0) *(float2*)(out + (size_t)row * 2) = make_float2(acc0, acc1);
}

// ---------------- canary ----------------
__global__ void k_check(const int* __restrict__ deg, const unsigned short* __restrict__ s1,
                        const unsigned short* __restrict__ h2, const unsigned short* __restrict__ h1,
                        float* __restrict__ out, int hostFail) {
    if (threadIdx.x != 0 || blockIdx.x != 0) return;
    float sentinel = 0.f;
    if (hostFail) sentinel = (float)hostFail;
    else {
        int d = deg[NN + 1234];
        if (d < 0 || d > 100000) sentinel = 100.0f;
        else {
            float sa = 0.f;
            for (int j = 0; j < DD; ++j) sa += fabsf(b2f((unsigned int)s1[777 * DD + j]));
            if (!(sa > 0.f)) sentinel = 200.0f;
            else {
                float sb = 0.f;
                for (int j = 0; j < 256; ++j) sb += fabsf(b2f((unsigned int)h2[(size_t)555 * 256 + j]));
                if (!(sb > 0.f)) sentinel = 300.0f;
                else {
                    float sc = 0.f;
                    for (int j = 0; j < DD; ++j) sc += fabsf(b2f((unsigned int)h1[(size_t)444 * DD + j]));
                    if (!(sc > 0.f)) sentinel = 400.0f;
                }
            }
        }
    }
    if (sentinel != 0.f) out[0] = sentinel;
}

// ---------------- workspace layout (bytes, 16-aligned) ----------------
static constexpr size_t O_DEG  = 0;            // 4N int = 800000
static constexpr size_t O_RS   = 800000;       // 4N f32 -> 1600000
static constexpr size_t O_ELL0 = 1600000;      // 12.8M -> 14400000
static constexpr size_t O_ELL1 = 14400000;     // -> 27200000
static constexpr size_t O_H2   = 1600000;      // overlay: h2 (25.6M) after ells die
static constexpr size_t O_S0   = 27200000;     // 12.8M -> 40000000 ; h1 overlays
static constexpr size_t O_H1   = 27200000;
static constexpr size_t O_S1   = 40000000;     // -> 52800000
static constexpr size_t O_AG0  = 52800000;     // -> 65600000
static constexpr size_t O_AG1  = 65600000;     // -> 78400000
static constexpr size_t O_WT   = 78400000;     // 5 weights bf16: 4*32KB + 64KB = 196608
static constexpr size_t O_BNS  = 78596608;     // 1024
static constexpr size_t O_BNAB = 78597632;     // 1024
static constexpr size_t O_END  = 78598656;

extern "C" void kernel_launch(void* const* d_in, const int* in_sizes, int n_in,
                              void* d_out, int out_size, void* d_ws, size_t ws_size,
                              hipStream_t stream) {
    const float* xA    = (const float*)d_in[0];
    const float* xB    = (const float*)d_in[1];
    const int* src0 = (const int*)d_in[2];
    const int* dst0 = (const int*)d_in[3];
    const int* src1 = (const int*)d_in[4];
    const int* dst1 = (const int*)d_in[5];
    const float* W1r0  = (const float*)d_in[6];
    const float* b1r0  = (const float*)d_in[7];
    const float* W1r1  = (const float*)d_in[8];
    const float* b1r1  = (const float*)d_in[9];
    const float* W2r0  = (const float*)d_in[10];
    const float* b2r0  = (const float*)d_in[11];
    const float* W2r1  = (const float*)d_in[12];
    const float* b2r1  = (const float*)d_in[13];
    const float* Wm1   = (const float*)d_in[14];
    const float* gamma = (const float*)d_in[15];
    const float* beta  = (const float*)d_in[16];
    const float* Wm2   = (const float*)d_in[17];

    char* ws = (char*)d_ws;
    int*   deg  = (int*)(ws + O_DEG);
    float* rs   = (float*)(ws + O_RS);
    int*   ell0 = (int*)(ws + O_ELL0);
    int*   ell1 = (int*)(ws + O_ELL1);
    unsigned short* s0  = (unsigned short*)(ws + O_S0);
    unsigned short* s1  = (unsigned short*)(ws + O_S1);
    unsigned short* ag0 = (unsigned short*)(ws + O_AG0);
    unsigned short* ag1 = (unsigned short*)(ws + O_AG1);
    unsigned short* h2  = (unsigned short*)(ws + O_H2);
    unsigned short* h1  = (unsigned short*)(ws + O_H1);
    unsigned short* wt  = (unsigned short*)(ws + O_WT);
    float* bns  = (float*)(ws + O_BNS);
    float* bnab = (float*)(ws + O_BNAB);
    float* out  = (float*)d_out;

    int hostFail = 0;
    if (ws_size < O_END) hostFail = 700;
    else if (n_in < 18) hostFail = 900;
    else if (in_sizes[0] != NN * DD) hostFail = 800;
    else if (in_sizes[2] != NE) hostFail = 850;

    if (!hostFail) {
        k_zero<<<(200000 + 255) / 256, 256, 0, stream>>>(deg, 200000);
        k_zero<<<1, 256, 0, stream>>>((int*)bns, 256);

        const int EB = (NE + 255) / 256;
        k_build<<<EB, 256, 0, stream>>>(src0, dst0, src1, dst1, deg, ell0, ell1);
        k_rs<<<(4 * NN + 255) / 256, 256, 0, stream>>>(deg, rs);
        k_scale_cast<<<dim3(12500, 2), 256, 0, stream>>>(xA, xB, rs, s0, s1);
        k_prepw<<<dim3(128, 5), 256, 0, stream>>>(W1r0, W1r1, W2r0, W2r1, Wm1, wt);

        const int AB = (NN * 64 + 255) / 256;   // wave per node
        const int GB = (NN + 63) / 64;          // 782

        // conv1 r0 (A->B): agg(xA over ell0, din0) -> relu(.@W1+b)*rs_dout1 -> s0 (becomes hB table)
        k_agg<<<AB, 256, 0, stream>>>(s0, ell0, deg + NN, rs + NN, ag0);
        k_gemm<1,1,1><<<GB, 256, 0, stream>>>(ag0, 128, 128, wt, b1r0, rs + 2 * NN, s0, 128, 0);
        // conv1 r1 (B->A) -> s1 (becomes hA table, pre-scaled by rs_dout0)
        k_agg<<<AB, 256, 0, stream>>>(s1, ell1, deg + 3 * NN, rs + 3 * NN, ag0);
        k_gemm<1,1,1><<<GB, 256, 0, stream>>>(ag0, 128, 128, wt + 16384, b1r1, rs, s1, 128, 0);
        // conv2 aggregations (both before gemms so ells die before h2 overlay is written)
        k_agg<<<AB, 256, 0, stream>>>(s1, ell0, deg + NN, rs + NN, ag0);        // hA via r0 -> dst B
        k_agg<<<AB, 256, 0, stream>>>(s0, ell1, deg + 3 * NN, rs + 3 * NN, ag1); // hB via r1 -> dst A
        // conv2 gemms -> h2 = [h2A | h2B]
        k_gemm<0,1,0><<<GB, 256, 0, stream>>>(ag0, 128, 128, wt + 32768, b2r0, nullptr, h2, 256, 128);
        k_gemm<0,1,0><<<GB, 256, 0, stream>>>(ag1, 128, 128, wt + 49152, b2r1, nullptr, h2, 256, 0);
        // MLP: h1 = h2 @ Wm1  (K=256, single kernel)
        k_gemm<0,0,0><<<GB, 256, 0, stream>>>(h2, 256, 256, wt + 65536, nullptr, nullptr, h1, 128, 0);

        k_bnstats<<<100, 256, 0, stream>>>(h1, bns);
        k_bnfinal<<<1, 128, 0, stream>>>(bns, gamma, beta, bnab);
        k_head<<<12500, 256, 0, stream>>>(h1, bnab, Wm2, out);
    }
    k_check<<<1, 64, 0, stream>>>(deg, s1, h2, h1, out, hostFail);
}